// Round 3
// baseline (5350.269 us; speedup 1.0000x reference)
//
#include <hip/hip_runtime.h>

// R13: hybrid MFMA+VALU column split. R10 interval (1021cy/step) is fully
// explained by matrix-pipe throughput: 256 MFMAs/step/CU at ~4cy/CU each
// (16x replicated-M matvec waste). Scheduling can't fix that; offloading
// half the columns to the idle VALU via v_dot2_f32_f16 (2 f16 MACs/instr,
// f32 accum = same numeric class) can.
// Per wave g (cols [64g,64g+64)):
//  - MFMA half: tiles T0/T1 = cols 64g+[0,32). 16 MFMAs (was 32), 4 chains
//    of depth 4. Owner lanes q<2 read chain reg0 (any C row is valid since
//    A rows are replicated h).
//  - VALU half: cols 64g+32+v, v=lane&31; each col split K in half across
//    lane pairs (l, l^32): 64 fdot2/lane, partner sum via __shfl_xor(32).
//    acc0 of the owner half (p=1) is seeded with the proj value.
//  - Ownership collapses to mycol = 64g+lane for ALL lanes (write/out/tau).
// Reverted R12's masked-ah reads (broadcast reads were already free; mask
// cost +148cy/step in exec-mask overhead). Kept PRE=2*log2e prescale.
// 64 WGs (1/CU) x 256 thr (4 waves, 1/SIMD). VGPR ~340 (<512, still 1
// wave/SIMD by design).

typedef _Float16 half8 __attribute__((ext_vector_type(8)));
typedef _Float16 half4 __attribute__((ext_vector_type(4)));
typedef _Float16 h2    __attribute__((ext_vector_type(2)));
typedef float    f32x4 __attribute__((ext_vector_type(4)));

union H8u { half8 v; h2 p[4]; };

#define LGKM_BARRIER() asm volatile("s_waitcnt lgkmcnt(0)\n\ts_barrier" ::: "memory")

__device__ __forceinline__ half8 cvt8s(float4 v0, float4 v1, float s) {
    half8 hv;
    hv[0]=(_Float16)(v0.x*s); hv[1]=(_Float16)(v0.y*s);
    hv[2]=(_Float16)(v0.z*s); hv[3]=(_Float16)(v0.w*s);
    hv[4]=(_Float16)(v1.x*s); hv[5]=(_Float16)(v1.y*s);
    hv[6]=(_Float16)(v1.z*s); hv[7]=(_Float16)(v1.w*s);
    return hv;
}
__device__ __forceinline__ half4 cvt4(float4 v) {
    half4 hv;
    hv[0]=(_Float16)v.x; hv[1]=(_Float16)v.y;
    hv[2]=(_Float16)v.z; hv[3]=(_Float16)v.w;
    return hv;
}

__global__ void __launch_bounds__(256, 1)
ltc_fused(const float* __restrict__ x,      // [B,T,128]
          const float* __restrict__ W_in,   // [256,128]
          const float* __restrict__ b_in,   // [256]
          const float* __restrict__ W_rec,  // [256,256]
          const float* __restrict__ b_rec,  // [256]
          const float* __restrict__ tau,    // [256]
          const int*   __restrict__ num_layers,
          float*       __restrict__ out,    // [B,256]
          int T)
{
    const int b    = blockIdx.x;
    const int tid  = threadIdx.x;
    const int lane = tid & 63;
    const int g    = tid >> 6;             // wave: out-cols [64g, 64g+64)
    const int n    = lane & 15;
    const int q    = lane >> 4;
    const int p    = lane >> 5;            // K-half for VALU path
    const int L    = num_layers[0];
    const int mycol = 64*g + lane;         // this lane's owned column

    __shared__ _Float16 hbuf[2][256];           // h, PLAIN layout, dbuf
    __shared__ _Float16 xstage[2][16][16][8];   // x chunk, A-frag order
    __shared__ _Float16 pchunk[32][4][16][4];   // proj chunk [ts][g][n][t4]

    const float PRE = 2.8853900817779268f;      // 2*log2(e)

    // ---- MFMA B-frags: W_rec tiles 0,1 only (cols 64g+[0,32)) ----
    half8 bh[2][8];
#pragma unroll
    for (int t = 0; t < 2; ++t) {
        const int col = 64*g + 16*t + n;
        const float* rp = &W_rec[col * 256 + 8*q];
#pragma unroll
        for (int i = 0; i < 8; ++i)
            bh[t][i] = cvt8s(*(const float4*)&rp[32*i],
                             *(const float4*)&rp[32*i + 4], PRE);
    }
    // ---- VALU weights: col 64g+32+(lane&31), K-half [128p,128p+128) ----
    h2 wv[64];
    {
        const int c  = 64*g + 32 + (lane & 31);
        const float* wp = &W_rec[c * 256 + 128*p];
#pragma unroll
        for (int j = 0; j < 32; ++j) {
            float4 w4 = *(const float4*)&wp[4*j];
            h2 a; a[0] = (_Float16)(w4.x * PRE); a[1] = (_Float16)(w4.y * PRE);
            h2 c2; c2[0] = (_Float16)(w4.z * PRE); c2[1] = (_Float16)(w4.w * PRE);
            wv[2*j]   = a;
            wv[2*j+1] = c2;
        }
    }
    // ---- proj B-frags (all 4 tiles) + fused bias ----
    half8 bx[4][4];
    float biasv[4];
#pragma unroll
    for (int t4 = 0; t4 < 4; ++t4) {
        const int col = 64*g + 16*t4 + n;
        const float* ip = &W_in[col * 128 + 8*q];
#pragma unroll
        for (int i = 0; i < 4; ++i)
            bx[t4][i] = cvt8s(*(const float4*)&ip[32*i],
                              *(const float4*)&ip[32*i + 4], PRE);
        biasv[t4] = (b_in[col] + b_rec[col]) * PRE;
    }
    const float sj   = 0.1f / fminf(fmaxf(tau[mycol], 0.1f), 5.0f);
    const float nsj2 = -2.0f * sj;
    float hj = 0.0f;

    hbuf[0][tid] = (_Float16)0.0f;         // zero h buffer 0 (256 thr)

    const float* xb  = x + (size_t)b * T * 128;
    const int    t_u = tid >> 3;           // staging: timestep in chunk
    const int    c8  = tid & 7;            // staging: 16-f32 block index
    const int    Mts = t_u >> 4, ms = t_u & 15;

    // ---- chunk-0 prefetch into registers ----
    float4 xpre0, xpre1, xpre2, xpre3;
    {
        int tg = t_u; if (tg > T - 1) tg = T - 1;
        const float4* src = (const float4*)(xb + (size_t)tg * 128 + 16*c8);
        xpre0 = src[0]; xpre1 = src[1]; xpre2 = src[2]; xpre3 = src[3];
    }

    int hb = 0;
    for (int tc = 0; tc < T; tc += 32) {
        // ---- stage chunk from regs (vmcnt wait folds in here) ----
        *(half4*)&xstage[Mts][2*c8    ][ms][0] = cvt4(xpre0);
        *(half4*)&xstage[Mts][2*c8    ][ms][4] = cvt4(xpre1);
        *(half4*)&xstage[Mts][2*c8 + 1][ms][0] = cvt4(xpre2);
        *(half4*)&xstage[Mts][2*c8 + 1][ms][4] = cvt4(xpre3);
        __syncthreads();

        // ---- project chunk: proj = (x·W_in^T + b_in + b_rec) * PRE ----
#pragma unroll
        for (int Mt = 0; Mt < 2; ++Mt) {
            half8 ax[4];
#pragma unroll
            for (int ks = 0; ks < 4; ++ks)
                ax[ks] = *(const half8*)&xstage[Mt][4*ks + q][n][0];
            f32x4 pa[4];
#pragma unroll
            for (int t4 = 0; t4 < 4; ++t4)
                pa[t4] = (f32x4){biasv[t4], biasv[t4], biasv[t4], biasv[t4]};
#pragma unroll
            for (int ks = 0; ks < 4; ++ks)
#pragma unroll
                for (int t4 = 0; t4 < 4; ++t4)
                    pa[t4] = __builtin_amdgcn_mfma_f32_16x16x32_f16(
                        ax[ks], bx[t4][ks], pa[t4], 0, 0, 0);
#pragma unroll
            for (int r = 0; r < 4; ++r) {
                half4 pk;
                pk[0] = (_Float16)pa[0][r]; pk[1] = (_Float16)pa[1][r];
                pk[2] = (_Float16)pa[2][r]; pk[3] = (_Float16)pa[3][r];
                *(half4*)&pchunk[16*Mt + 4*q + r][g][n][0] = pk;
            }
        }
        __syncthreads();

        // ---- issue next chunk's global loads; fly across lgkm barriers ----
        {
            const int nc = (tc + 32 < T) ? tc + 32 : tc;
            int tg = nc + t_u; if (tg > T - 1) tg = T - 1;
            const float4* src = (const float4*)(xb + (size_t)tg * 128 + 16*c8);
            xpre0 = src[0]; xpre1 = src[1]; xpre2 = src[2]; xpre3 = src[3];
        }

        // ---- steady scan: LDS-only, lgkm-barriers only ----
        const int tlen = (T - tc < 32) ? (T - tc) : 32;
        half4 xv_cur = *(const half4*)&pchunk[0][g][n][0];   // ts=0 xc
        for (int ts = 0; ts < tlen; ++ts) {
            float xq4[4];
#pragma unroll
            for (int t4 = 0; t4 < 4; ++t4) xq4[t4] = (float)xv_cur[t4];
            const float xc0   = xq4[0];
            const float xc1   = xq4[1];
            const float xvalu = (q & 1) ? xq4[3] : xq4[2];
            half4 xv_nxt = xv_cur;

            for (int l = 0; l < L; ++l) {
                // A-frags (broadcast per q-group; issued first, in-order)
                half8 ah[8];
#pragma unroll
                for (int i = 0; i < 8; ++i)
                    ah[i] = *(const half8*)&hbuf[hb][32*i + 8*q];
                // VALU h pairs: this lane's K-half (broadcast per p-half)
                H8u hp[16];
#pragma unroll
                for (int j = 0; j < 16; ++j)
                    hp[j].v = *(const half8*)&hbuf[hb][128*p + 8*j];
                if (l == 0) {
                    const int tsn = (ts + 1 < tlen) ? ts + 1 : ts;
                    xv_nxt = *(const half4*)&pchunk[tsn][g][n][0];
                }

                // term1 = h + s*(1-h): off critical path (needs only hj)
                const float term1 = __builtin_fmaf(sj, 1.0f - hj, hj);

                // ---- MFMA half: 2 tiles x 2 chains (depth 4) ----
                f32x4 C0a = (f32x4){xc0, xc0, xc0, xc0};
                f32x4 C1a = (f32x4){xc1, xc1, xc1, xc1};
                f32x4 C0b = (f32x4){0.f, 0.f, 0.f, 0.f};
                f32x4 C1b = (f32x4){0.f, 0.f, 0.f, 0.f};
#pragma unroll
                for (int i2 = 0; i2 < 4; ++i2) {
                    C0a = __builtin_amdgcn_mfma_f32_16x16x32_f16(
                        ah[i2],     bh[0][i2],     C0a, 0, 0, 0);
                    C1a = __builtin_amdgcn_mfma_f32_16x16x32_f16(
                        ah[i2],     bh[1][i2],     C1a, 0, 0, 0);
                    C0b = __builtin_amdgcn_mfma_f32_16x16x32_f16(
                        ah[4 + i2], bh[0][4 + i2], C0b, 0, 0, 0);
                    C1b = __builtin_amdgcn_mfma_f32_16x16x32_f16(
                        ah[4 + i2], bh[1][4 + i2], C1b, 0, 0, 0);
                }

                // ---- VALU half: 64 fdot2 over 4 accumulators ----
                float acc0 = (p != 0) ? xvalu : 0.0f;
                float acc1 = 0.0f, acc2 = 0.0f, acc3 = 0.0f;
#pragma unroll
                for (int j = 0; j < 16; j += 4) {
#pragma unroll
                    for (int u = 0; u < 4; ++u) {
                        acc0 = __builtin_amdgcn_fdot2(hp[j  ].p[u], wv[4*j      + u], acc0, false);
                        acc1 = __builtin_amdgcn_fdot2(hp[j+1].p[u], wv[4*(j+1)  + u], acc1, false);
                        acc2 = __builtin_amdgcn_fdot2(hp[j+2].p[u], wv[4*(j+2)  + u], acc2, false);
                        acc3 = __builtin_amdgcn_fdot2(hp[j+3].p[u], wv[4*(j+3)  + u], acc3, false);
                    }
                }
                float sv = (acc0 + acc1) + (acc2 + acc3);
                float so = __shfl_xor(sv, 32);   // partner's K-half
                float zv = sv + so;

                // MFMA tail: owner lanes q<2 read chain reg0 of their tile
                float zt0 = C0a[0] + C0b[0];
                float zt1 = C1a[0] + C1b[0];
                float zm  = (q & 1) ? zt1 : zt0;
                float z   = (p != 0) ? zv : zm;

                float e;   // e = e^{2*z_true} = 2^{z''} (prescaled weights)
                asm("v_exp_f32 %0, %1\n\ts_nop 0" : "=v"(e) : "v"(z));
                float r = __builtin_amdgcn_rcpf(e + 1.0f);      // 1/(e+1)
                hj = __builtin_fmaf(nsj2, r, term1);            // h+s*(tanh-h)
                hbuf[hb ^ 1][mycol] = (_Float16)hj;
                LGKM_BARRIER();
                hb ^= 1;
            }
            xv_cur = xv_nxt;
        }
    }

    out[(size_t)b * 256 + mycol] = hj;
}

extern "C" void kernel_launch(void* const* d_in, const int* in_sizes, int n_in,
                              void* d_out, int out_size, void* d_ws, size_t ws_size,
                              hipStream_t stream) {
    const float* x     = (const float*)d_in[0];
    const float* W_in  = (const float*)d_in[1];
    const float* b_in  = (const float*)d_in[2];
    const float* W_rec = (const float*)d_in[3];
    const float* b_rec = (const float*)d_in[4];
    const float* tau   = (const float*)d_in[5];
    const int*   numl  = (const int*)d_in[6];

    const int H = in_sizes[2];            // 256
    const int I = in_sizes[1] / H;        // 128
    const int B = out_size / H;           // 64
    const int T = in_sizes[0] / (B * I);  // 4096

    ltc_fused<<<B, 256, 0, stream>>>(x, W_in, b_in, W_rec, b_rec, tau,
                                     numl, (float*)d_out, T);
}

// Round 4
// 3647.537 us; speedup vs baseline: 1.4668x; 1.4668x over previous
//
#include <hip/hip_runtime.h>

// R14: recovery to R10 structure + validated/cheap shaves only.
// History: R10=3488us (1021cy/step, best). R12 masked-ah = +147cy (broadcast
// reads were already ~free; mask added exec overhead). R13 in-wave
// MFMA+fdot2 hybrid = +374cy (single wave issues in-order: VALU work adds
// to the serial path; shfl_xor DS-latency on tail). Calibration from R13:
// broadcast ds_read_b128 ~2-3cy each -> DS pipe is NOT the bottleneck.
// Step critical path (510cy/layer): barrier + read-lat(120) + MFMA pipe
// (32x ~5cy=155) + mfma-lat(40) + tail(~70) + write/lgkm/barrier(~100).
// This round:
//  - UNmasked ah reads (revert R12).
//  - PRE=2*log2(e) prescale of W_rec/W_in/bias: e^{2z} = v_exp_f32(z'')
//    directly (validated absmax 0.0039 in R12/R13).
//  - Zero-init all 16 MFMA chains from one shared zero C-in (D!=C is
//    legal), fold xc into the tail as one add; xc tile-select hoisted to
//    once per timestep. Kills 16 v_mov C-inits per layer.
// 64 WGs (1/CU) x 256 thr (4 waves, 1/SIMD). Wave g owns cols [64g,64g+64);
// lane (n=lane&15,q=lane>>4) owns col 64g+16q+n at the epilogue.

typedef _Float16 half8 __attribute__((ext_vector_type(8)));
typedef _Float16 half4 __attribute__((ext_vector_type(4)));
typedef float    f32x4 __attribute__((ext_vector_type(4)));

#define LGKM_BARRIER() asm volatile("s_waitcnt lgkmcnt(0)\n\ts_barrier" ::: "memory")

__device__ __forceinline__ half8 cvt8s(float4 v0, float4 v1, float s) {
    half8 hv;
    hv[0]=(_Float16)(v0.x*s); hv[1]=(_Float16)(v0.y*s);
    hv[2]=(_Float16)(v0.z*s); hv[3]=(_Float16)(v0.w*s);
    hv[4]=(_Float16)(v1.x*s); hv[5]=(_Float16)(v1.y*s);
    hv[6]=(_Float16)(v1.z*s); hv[7]=(_Float16)(v1.w*s);
    return hv;
}
__device__ __forceinline__ half4 cvt4(float4 v) {
    half4 hv;
    hv[0]=(_Float16)v.x; hv[1]=(_Float16)v.y;
    hv[2]=(_Float16)v.z; hv[3]=(_Float16)v.w;
    return hv;
}

// select chain-q's reg0 without dynamic indexing (3 cndmask)
__device__ __forceinline__ float sel4(const f32x4 (&a)[4], int k) {
    float v0 = (k & 2) ? a[2][0] : a[0][0];
    float v1 = (k & 2) ? a[3][0] : a[1][0];
    return (k & 1) ? v1 : v0;
}
// a[k] for runtime k in 0..3 (3 cndmask)
__device__ __forceinline__ float selq(const float (&a)[4], int k) {
    float v0 = (k & 2) ? a[2] : a[0];
    float v1 = (k & 2) ? a[3] : a[1];
    return (k & 1) ? v1 : v0;
}

__global__ void __launch_bounds__(256, 1)
ltc_fused(const float* __restrict__ x,      // [B,T,128]
          const float* __restrict__ W_in,   // [256,128]
          const float* __restrict__ b_in,   // [256]
          const float* __restrict__ W_rec,  // [256,256]
          const float* __restrict__ b_rec,  // [256]
          const float* __restrict__ tau,    // [256]
          const int*   __restrict__ num_layers,
          float*       __restrict__ out,    // [B,256]
          int T)
{
    const int b    = blockIdx.x;
    const int tid  = threadIdx.x;
    const int lane = tid & 63;
    const int g    = tid >> 6;             // wave: out-cols [64g, 64g+64)
    const int n    = lane & 15;
    const int q    = lane >> 4;
    const int L    = num_layers[0];
    const int mycol = 64*g + 16*q + n;     // this lane's epilogue column

    __shared__ _Float16 hbuf[2][256];           // h, PLAIN layout, dbuf
    __shared__ _Float16 xstage[2][16][16][8];   // x chunk, A-frag order
    __shared__ _Float16 pchunk[32][4][16][4];   // proj chunk [ts][g][n][t4]

    // ---- stationary B-frags: W_rec (4x8) + W_in (4x4), f16, prescaled ----
    const float PRE = 2.8853900817779268f;      // 2*log2(e)
    half8 bh[4][8];
    half8 bx[4][4];
    float biasv[4];
#pragma unroll
    for (int t4 = 0; t4 < 4; ++t4) {
        const int col = 64*g + 16*t4 + n;
        const float* rp = &W_rec[col * 256 + 8*q];
#pragma unroll
        for (int i = 0; i < 8; ++i)
            bh[t4][i] = cvt8s(*(const float4*)&rp[32*i],
                              *(const float4*)&rp[32*i + 4], PRE);
        const float* ip = &W_in[col * 128 + 8*q];
#pragma unroll
        for (int i = 0; i < 4; ++i)
            bx[t4][i] = cvt8s(*(const float4*)&ip[32*i],
                              *(const float4*)&ip[32*i + 4], PRE);
        biasv[t4] = (b_in[col] + b_rec[col]) * PRE;
    }
    const float sj   = 0.1f / fminf(fmaxf(tau[mycol], 0.1f), 5.0f);
    const float nsj2 = -2.0f * sj;
    float hj = 0.0f;

    hbuf[0][tid] = (_Float16)0.0f;         // zero h buffer 0 (256 thr)

    const float* xb  = x + (size_t)b * T * 128;
    const int    t_u = tid >> 3;           // staging: timestep in chunk
    const int    c8  = tid & 7;            // staging: 16-f32 block index
    const int    Mts = t_u >> 4, ms = t_u & 15;

    // ---- chunk-0 prefetch into registers ----
    float4 xpre0, xpre1, xpre2, xpre3;
    {
        int tg = t_u; if (tg > T - 1) tg = T - 1;
        const float4* src = (const float4*)(xb + (size_t)tg * 128 + 16*c8);
        xpre0 = src[0]; xpre1 = src[1]; xpre2 = src[2]; xpre3 = src[3];
    }

    int hb = 0;
    for (int tc = 0; tc < T; tc += 32) {
        // ---- stage chunk from regs (vmcnt wait folds in here) ----
        *(half4*)&xstage[Mts][2*c8    ][ms][0] = cvt4(xpre0);
        *(half4*)&xstage[Mts][2*c8    ][ms][4] = cvt4(xpre1);
        *(half4*)&xstage[Mts][2*c8 + 1][ms][0] = cvt4(xpre2);
        *(half4*)&xstage[Mts][2*c8 + 1][ms][4] = cvt4(xpre3);
        __syncthreads();

        // ---- project chunk: proj = (x·W_in^T + b_in + b_rec) * PRE ----
#pragma unroll
        for (int Mt = 0; Mt < 2; ++Mt) {
            half8 ax[4];
#pragma unroll
            for (int ks = 0; ks < 4; ++ks)
                ax[ks] = *(const half8*)&xstage[Mt][4*ks + q][n][0];
            f32x4 pa[4];
#pragma unroll
            for (int t4 = 0; t4 < 4; ++t4)
                pa[t4] = (f32x4){biasv[t4], biasv[t4], biasv[t4], biasv[t4]};
#pragma unroll
            for (int ks = 0; ks < 4; ++ks)
#pragma unroll
                for (int t4 = 0; t4 < 4; ++t4)
                    pa[t4] = __builtin_amdgcn_mfma_f32_16x16x32_f16(
                        ax[ks], bx[t4][ks], pa[t4], 0, 0, 0);
#pragma unroll
            for (int r = 0; r < 4; ++r) {
                half4 pk;
                pk[0] = (_Float16)pa[0][r]; pk[1] = (_Float16)pa[1][r];
                pk[2] = (_Float16)pa[2][r]; pk[3] = (_Float16)pa[3][r];
                *(half4*)&pchunk[16*Mt + 4*q + r][g][n][0] = pk;
            }
        }
        __syncthreads();

        // ---- issue next chunk's global loads; fly across lgkm barriers ----
        {
            const int nc = (tc + 32 < T) ? tc + 32 : tc;
            int tg = nc + t_u; if (tg > T - 1) tg = T - 1;
            const float4* src = (const float4*)(xb + (size_t)tg * 128 + 16*c8);
            xpre0 = src[0]; xpre1 = src[1]; xpre2 = src[2]; xpre3 = src[3];
        }

        // ---- steady scan: LDS-only, lgkm-barriers only ----
        const int tlen = (T - tc < 32) ? (T - tc) : 32;
        half4 xv_cur = *(const half4*)&pchunk[0][g][n][0];   // ts=0 xc
        for (int ts = 0; ts < tlen; ++ts) {
            float xq4[4];
#pragma unroll
            for (int t4 = 0; t4 < 4; ++t4) xq4[t4] = (float)xv_cur[t4];
            // this lane's tile-q xc, selected ONCE per ts (3 cndmask)
            const float xcq = selq(xq4, q);
            half4 xv_nxt = xv_cur;

            for (int l = 0; l < L; ++l) {
                half8 ah[8];
#pragma unroll
                for (int i = 0; i < 8; ++i)
                    ah[i] = *(const half8*)&hbuf[hb][32*i + 8*q];
                if (l == 0) {
                    const int tsn = (ts + 1 < tlen) ? ts + 1 : ts;
                    xv_nxt = *(const half4*)&pchunk[tsn][g][n][0];
                }

                // term1 = h + s*(1-h): off critical path (needs only hj)
                const float term1 = __builtin_fmaf(sj, 1.0f - hj, hj);

                // 16 chains, depth 2, all starting from a SHARED zero C-in
                // (MFMA D may differ from C); xc added in the tail.
                const f32x4 zz = (f32x4){0.f, 0.f, 0.f, 0.f};
                f32x4 A0[4], A1[4], A2[4], A3[4];
#pragma unroll
                for (int t4 = 0; t4 < 4; ++t4) {
                    A0[t4] = __builtin_amdgcn_mfma_f32_16x16x32_f16(
                        ah[0], bh[t4][0], zz, 0, 0, 0);
                    A1[t4] = __builtin_amdgcn_mfma_f32_16x16x32_f16(
                        ah[2], bh[t4][2], zz, 0, 0, 0);
                    A2[t4] = __builtin_amdgcn_mfma_f32_16x16x32_f16(
                        ah[4], bh[t4][4], zz, 0, 0, 0);
                    A3[t4] = __builtin_amdgcn_mfma_f32_16x16x32_f16(
                        ah[6], bh[t4][6], zz, 0, 0, 0);
                }
#pragma unroll
                for (int t4 = 0; t4 < 4; ++t4) {
                    A0[t4] = __builtin_amdgcn_mfma_f32_16x16x32_f16(
                        ah[1], bh[t4][1], A0[t4], 0, 0, 0);
                    A1[t4] = __builtin_amdgcn_mfma_f32_16x16x32_f16(
                        ah[3], bh[t4][3], A1[t4], 0, 0, 0);
                    A2[t4] = __builtin_amdgcn_mfma_f32_16x16x32_f16(
                        ah[5], bh[t4][5], A2[t4], 0, 0, 0);
                    A3[t4] = __builtin_amdgcn_mfma_f32_16x16x32_f16(
                        ah[7], bh[t4][7], A3[t4], 0, 0, 0);
                }

                // tail: select this lane's tile (slot q), reg0 = row 4q
                float z = ((sel4(A0, q) + sel4(A1, q))
                         + (sel4(A2, q) + sel4(A3, q))) + xcq;
                float e;   // e = e^{2*z_true} = 2^{z''} (prescaled weights)
                asm("v_exp_f32 %0, %1\n\ts_nop 0" : "=v"(e) : "v"(z));
                float r = __builtin_amdgcn_rcpf(e + 1.0f);      // 1/(e+1)
                hj = __builtin_fmaf(nsj2, r, term1);            // h+s*(tanh-h)
                hbuf[hb ^ 1][mycol] = (_Float16)hj;
                LGKM_BARRIER();
                hb ^= 1;
            }
            xv_cur = xv_nxt;
        }
    }

    out[(size_t)b * 256 + mycol] = hj;
}

extern "C" void kernel_launch(void* const* d_in, const int* in_sizes, int n_in,
                              void* d_out, int out_size, void* d_ws, size_t ws_size,
                              hipStream_t stream) {
    const float* x     = (const float*)d_in[0];
    const float* W_in  = (const float*)d_in[1];
    const float* b_in  = (const float*)d_in[2];
    const float* W_rec = (const float*)d_in[3];
    const float* b_rec = (const float*)d_in[4];
    const float* tau   = (const float*)d_in[5];
    const int*   numl  = (const int*)d_in[6];

    const int H = in_sizes[2];            // 256
    const int I = in_sizes[1] / H;        // 128
    const int B = out_size / H;           // 64
    const int T = in_sizes[0] / (B * I);  // 4096

    ltc_fused<<<B, 256, 0, stream>>>(x, W_in, b_in, W_rec, b_rec, tau,
                                     numl, (float*)d_out, T);
}

// Round 6
// 3313.898 us; speedup vs baseline: 1.6145x; 1.1007x over previous
//
#include <hip/hip_runtime.h>

// R16 = R15 resubmitted verbatim (R5 bench was an infra failure: container
// acquire failed twice; no counters, no theory update).
// R15: issue-slot shaving on the R10/R14 structure. Model (calibrated by
// R13's +187cy for +190cy of added issue work): with 1 wave/SIMD the wave's
// serial issue stream is the resource. Per layer ~510cy = 32 MFMA x ~8cy
// port + ~40 VALU/DS x 2cy + ~170cy latency. This round removes ~20-25
// instr/layer of addressing/loop/select overhead:
//  - L==2 specialization: hb parity is static per layer -> ALL steady-loop
//    LDS addresses become one base VGPR + compile-time immediates (reads
//    64i+512*buf, writes 0/512, pchunk ts*512). No hb flip, no l-loop.
//    Generic-L fallback kept for correctness.
//  - per-ts x select: b64 read + 1 cndmask + 1 lshr(shamt=(q&1)*16) + 1 cvt
//    instead of 4 cvt + 3 cndmask.
//  - __builtin_amdgcn_exp2f replaces asm v_exp (drops s_nop).
// Kept: full (unmasked) broadcast ah reads, PRE=2*log2e prescale (absmax
// 0.0039 validated), 16 chains depth-2 from shared zero C-in, xcq in tail.
// 64 WGs (1/CU) x 256 thr (4 waves, 1/SIMD). Wave g owns cols [64g,64g+64);
// lane (n=lane&15,q=lane>>4) owns col 64g+16q+n.

typedef _Float16 half8 __attribute__((ext_vector_type(8)));
typedef _Float16 half4 __attribute__((ext_vector_type(4)));
typedef float    f32x4 __attribute__((ext_vector_type(4)));

#define LGKM_BARRIER() asm volatile("s_waitcnt lgkmcnt(0)\n\ts_barrier" ::: "memory")

__device__ __forceinline__ half8 cvt8s(float4 v0, float4 v1, float s) {
    half8 hv;
    hv[0]=(_Float16)(v0.x*s); hv[1]=(_Float16)(v0.y*s);
    hv[2]=(_Float16)(v0.z*s); hv[3]=(_Float16)(v0.w*s);
    hv[4]=(_Float16)(v1.x*s); hv[5]=(_Float16)(v1.y*s);
    hv[6]=(_Float16)(v1.z*s); hv[7]=(_Float16)(v1.w*s);
    return hv;
}
__device__ __forceinline__ half4 cvt4(float4 v) {
    half4 hv;
    hv[0]=(_Float16)v.x; hv[1]=(_Float16)v.y;
    hv[2]=(_Float16)v.z; hv[3]=(_Float16)v.w;
    return hv;
}

// select chain-k's reg0 without dynamic indexing (3 cndmask)
__device__ __forceinline__ float sel4(const f32x4 (&a)[4], int k) {
    float v0 = (k & 2) ? a[2][0] : a[0][0];
    float v1 = (k & 2) ? a[3][0] : a[1][0];
    return (k & 1) ? v1 : v0;
}

__global__ void __launch_bounds__(256, 1)
ltc_fused(const float* __restrict__ x,      // [B,T,128]
          const float* __restrict__ W_in,   // [256,128]
          const float* __restrict__ b_in,   // [256]
          const float* __restrict__ W_rec,  // [256,256]
          const float* __restrict__ b_rec,  // [256]
          const float* __restrict__ tau,    // [256]
          const int*   __restrict__ num_layers,
          float*       __restrict__ out,    // [B,256]
          int T)
{
    const int b    = blockIdx.x;
    const int tid  = threadIdx.x;
    const int lane = tid & 63;
    const int g    = tid >> 6;             // wave: out-cols [64g, 64g+64)
    const int n    = lane & 15;
    const int q    = lane >> 4;
    const int L    = num_layers[0];
    const int mycol = 64*g + 16*q + n;     // this lane's epilogue column
    const unsigned shamt = (unsigned)((q & 1) << 4);   // f16 select shift

    __shared__ _Float16 hbuf[2][256];           // h, PLAIN layout, dbuf
    __shared__ _Float16 xstage[2][16][16][8];   // x chunk, A-frag order
    __shared__ _Float16 pchunk[32][4][16][4];   // proj chunk [ts][g][n][t4]

    // ---- stationary B-frags: W_rec (4x8) + W_in (4x4), f16, prescaled ----
    const float PRE = 2.8853900817779268f;      // 2*log2(e)
    half8 bh[4][8];
    half8 bx[4][4];
    float biasv[4];
#pragma unroll
    for (int t4 = 0; t4 < 4; ++t4) {
        const int col = 64*g + 16*t4 + n;
        const float* rp = &W_rec[col * 256 + 8*q];
#pragma unroll
        for (int i = 0; i < 8; ++i)
            bh[t4][i] = cvt8s(*(const float4*)&rp[32*i],
                              *(const float4*)&rp[32*i + 4], PRE);
        const float* ip = &W_in[col * 128 + 8*q];
#pragma unroll
        for (int i = 0; i < 4; ++i)
            bx[t4][i] = cvt8s(*(const float4*)&ip[32*i],
                              *(const float4*)&ip[32*i + 4], PRE);
        biasv[t4] = (b_in[col] + b_rec[col]) * PRE;
    }
    const float sj   = 0.1f / fminf(fmaxf(tau[mycol], 0.1f), 5.0f);
    const float nsj2 = -2.0f * sj;
    float hj = 0.0f;

    hbuf[0][tid] = (_Float16)0.0f;         // zero h buffer 0 (256 thr)

    const float* xb  = x + (size_t)b * T * 128;
    const int    t_u = tid >> 3;           // staging: timestep in chunk
    const int    c8  = tid & 7;            // staging: 16-f32 block index
    const int    Mts = t_u >> 4, ms = t_u & 15;

    // ---- chunk-0 prefetch into registers ----
    float4 xpre0, xpre1, xpre2, xpre3;
    {
        int tg = t_u; if (tg > T - 1) tg = T - 1;
        const float4* src = (const float4*)(xb + (size_t)tg * 128 + 16*c8);
        xpre0 = src[0]; xpre1 = src[1]; xpre2 = src[2]; xpre3 = src[3];
    }

// one recurrent layer: read hbuf[RB] (static), write hbuf[WB] (static)
#define LAYER(RB, WB, XCQ)                                                   \
    do {                                                                     \
        half8 ah[8];                                                         \
        _Pragma("unroll")                                                    \
        for (int i = 0; i < 8; ++i)                                          \
            ah[i] = *(const half8*)&hbuf[RB][32*i + 8*q];                    \
        const float term1 = __builtin_fmaf(sj, 1.0f - hj, hj);               \
        const f32x4 zz = (f32x4){0.f, 0.f, 0.f, 0.f};                        \
        f32x4 A0[4], A1[4], A2[4], A3[4];                                    \
        _Pragma("unroll")                                                    \
        for (int t4 = 0; t4 < 4; ++t4) {                                     \
            A0[t4] = __builtin_amdgcn_mfma_f32_16x16x32_f16(                 \
                ah[0], bh[t4][0], zz, 0, 0, 0);                              \
            A1[t4] = __builtin_amdgcn_mfma_f32_16x16x32_f16(                 \
                ah[2], bh[t4][2], zz, 0, 0, 0);                              \
            A2[t4] = __builtin_amdgcn_mfma_f32_16x16x32_f16(                 \
                ah[4], bh[t4][4], zz, 0, 0, 0);                              \
            A3[t4] = __builtin_amdgcn_mfma_f32_16x16x32_f16(                 \
                ah[6], bh[t4][6], zz, 0, 0, 0);                              \
        }                                                                    \
        _Pragma("unroll")                                                    \
        for (int t4 = 0; t4 < 4; ++t4) {                                     \
            A0[t4] = __builtin_amdgcn_mfma_f32_16x16x32_f16(                 \
                ah[1], bh[t4][1], A0[t4], 0, 0, 0);                          \
            A1[t4] = __builtin_amdgcn_mfma_f32_16x16x32_f16(                 \
                ah[3], bh[t4][3], A1[t4], 0, 0, 0);                          \
            A2[t4] = __builtin_amdgcn_mfma_f32_16x16x32_f16(                 \
                ah[5], bh[t4][5], A2[t4], 0, 0, 0);                          \
            A3[t4] = __builtin_amdgcn_mfma_f32_16x16x32_f16(                 \
                ah[7], bh[t4][7], A3[t4], 0, 0, 0);                          \
        }                                                                    \
        float z = ((sel4(A0, q) + sel4(A1, q))                               \
                 + (sel4(A2, q) + sel4(A3, q))) + (XCQ);                     \
        float e  = __builtin_amdgcn_exp2f(z);     /* e^{2z}, prescaled */    \
        float rr = __builtin_amdgcn_rcpf(e + 1.0f);                          \
        hj = __builtin_fmaf(nsj2, rr, term1);     /* h + s*(tanh-h) */       \
        hbuf[WB][mycol] = (_Float16)hj;                                      \
        LGKM_BARRIER();                                                      \
    } while (0)

    if (L == 2) {
        // ======== specialized L==2 path: fully static LDS addressing ====
        for (int tc = 0; tc < T; tc += 32) {
            *(half4*)&xstage[Mts][2*c8    ][ms][0] = cvt4(xpre0);
            *(half4*)&xstage[Mts][2*c8    ][ms][4] = cvt4(xpre1);
            *(half4*)&xstage[Mts][2*c8 + 1][ms][0] = cvt4(xpre2);
            *(half4*)&xstage[Mts][2*c8 + 1][ms][4] = cvt4(xpre3);
            __syncthreads();

#pragma unroll
            for (int Mt = 0; Mt < 2; ++Mt) {
                half8 ax[4];
#pragma unroll
                for (int ks = 0; ks < 4; ++ks)
                    ax[ks] = *(const half8*)&xstage[Mt][4*ks + q][n][0];
                f32x4 pa[4];
#pragma unroll
                for (int t4 = 0; t4 < 4; ++t4)
                    pa[t4] = (f32x4){biasv[t4], biasv[t4], biasv[t4], biasv[t4]};
#pragma unroll
                for (int ks = 0; ks < 4; ++ks)
#pragma unroll
                    for (int t4 = 0; t4 < 4; ++t4)
                        pa[t4] = __builtin_amdgcn_mfma_f32_16x16x32_f16(
                            ax[ks], bx[t4][ks], pa[t4], 0, 0, 0);
#pragma unroll
                for (int r = 0; r < 4; ++r) {
                    half4 pk;
                    pk[0] = (_Float16)pa[0][r]; pk[1] = (_Float16)pa[1][r];
                    pk[2] = (_Float16)pa[2][r]; pk[3] = (_Float16)pa[3][r];
                    *(half4*)&pchunk[16*Mt + 4*q + r][g][n][0] = pk;
                }
            }
            __syncthreads();

            // next chunk's global loads; fly across all steady barriers
            {
                const int nc = (tc + 32 < T) ? tc + 32 : tc;
                int tg = nc + t_u; if (tg > T - 1) tg = T - 1;
                const float4* src = (const float4*)(xb + (size_t)tg * 128 + 16*c8);
                xpre0 = src[0]; xpre1 = src[1]; xpre2 = src[2]; xpre3 = src[3];
            }

            const int tlen = (T - tc < 32) ? (T - tc) : 32;
#pragma unroll 2
            for (int ts = 0; ts < tlen; ++ts) {
                // xcq: b64 read + 1 cndmask + 1 lshr + 1 cvt
                const uint2 pv = *(const uint2*)&pchunk[ts][g][n][0];
                unsigned d = (q & 2) ? pv.y : pv.x;
                d >>= shamt;
                float xcq;
                { union { unsigned u; _Float16 h[2]; } uu; uu.u = d;
                  xcq = (float)uu.h[0]; }

                LAYER(0, 1, xcq);   // layer 1: buf0 -> buf1
                LAYER(1, 0, xcq);   // layer 2: buf1 -> buf0
            }
        }
    } else {
        // ======== generic-L fallback (R14 structure) ====================
        int hb = 0;
        for (int tc = 0; tc < T; tc += 32) {
            *(half4*)&xstage[Mts][2*c8    ][ms][0] = cvt4(xpre0);
            *(half4*)&xstage[Mts][2*c8    ][ms][4] = cvt4(xpre1);
            *(half4*)&xstage[Mts][2*c8 + 1][ms][0] = cvt4(xpre2);
            *(half4*)&xstage[Mts][2*c8 + 1][ms][4] = cvt4(xpre3);
            __syncthreads();

#pragma unroll
            for (int Mt = 0; Mt < 2; ++Mt) {
                half8 ax[4];
#pragma unroll
                for (int ks = 0; ks < 4; ++ks)
                    ax[ks] = *(const half8*)&xstage[Mt][4*ks + q][n][0];
                f32x4 pa[4];
#pragma unroll
                for (int t4 = 0; t4 < 4; ++t4)
                    pa[t4] = (f32x4){biasv[t4], biasv[t4], biasv[t4], biasv[t4]};
#pragma unroll
                for (int ks = 0; ks < 4; ++ks)
#pragma unroll
                    for (int t4 = 0; t4 < 4; ++t4)
                        pa[t4] = __builtin_amdgcn_mfma_f32_16x16x32_f16(
                            ax[ks], bx[t4][ks], pa[t4], 0, 0, 0);
#pragma unroll
                for (int r = 0; r < 4; ++r) {
                    half4 pk;
                    pk[0] = (_Float16)pa[0][r]; pk[1] = (_Float16)pa[1][r];
                    pk[2] = (_Float16)pa[2][r]; pk[3] = (_Float16)pa[3][r];
                    *(half4*)&pchunk[16*Mt + 4*q + r][g][n][0] = pk;
                }
            }
            __syncthreads();

            {
                const int nc = (tc + 32 < T) ? tc + 32 : tc;
                int tg = nc + t_u; if (tg > T - 1) tg = T - 1;
                const float4* src = (const float4*)(xb + (size_t)tg * 128 + 16*c8);
                xpre0 = src[0]; xpre1 = src[1]; xpre2 = src[2]; xpre3 = src[3];
            }

            const int tlen = (T - tc < 32) ? (T - tc) : 32;
            for (int ts = 0; ts < tlen; ++ts) {
                const uint2 pv = *(const uint2*)&pchunk[ts][g][n][0];
                unsigned d = (q & 2) ? pv.y : pv.x;
                d >>= shamt;
                float xcq;
                { union { unsigned u; _Float16 h[2]; } uu; uu.u = d;
                  xcq = (float)uu.h[0]; }

                for (int l = 0; l < L; ++l) {
                    if (hb == 0) LAYER(0, 1, xcq);
                    else         LAYER(1, 0, xcq);
                    hb ^= 1;
                }
            }
        }
        // h ends in hbuf[hb]; hj already holds this lane's value
    }
#undef LAYER

    out[(size_t)b * 256 + mycol] = hj;
}

extern "C" void kernel_launch(void* const* d_in, const int* in_sizes, int n_in,
                              void* d_out, int out_size, void* d_ws, size_t ws_size,
                              hipStream_t stream) {
    const float* x     = (const float*)d_in[0];
    const float* W_in  = (const float*)d_in[1];
    const float* b_in  = (const float*)d_in[2];
    const float* W_rec = (const float*)d_in[3];
    const float* b_rec = (const float*)d_in[4];
    const float* tau   = (const float*)d_in[5];
    const int*   numl  = (const int*)d_in[6];

    const int H = in_sizes[2];            // 256
    const int I = in_sizes[1] / H;        // 128
    const int B = out_size / H;           // 64
    const int T = in_sizes[0] / (B * I);  // 4096

    ltc_fused<<<B, 256, 0, stream>>>(x, W_in, b_in, W_rec, b_rec, tau,
                                     numl, (float*)d_out, T);
}

// Round 7
// 3236.855 us; speedup vs baseline: 1.6529x; 1.0238x over previous
//
#include <hip/hip_runtime.h>

// R17: 8 waves (512 thr) = 2 waves/SIMD for TLP bubble-filling.
// R16 (3225us, 945cy/step) analysis: MfmaUtil 13.9% global / 25% active-CU
// fraction => matrix pipe only ~56% busy on active CUs. Per layer ~472cy =
// ~264cy MFMA pipe + ~208cy serial non-MFMA (read latency, exp/rcp tail,
// write+lgkm+barrier) with NOTHING to fill the bubbles at 1 wave/SIMD.
// Fix: 8 waves/WG, 32 cols/wave (2 16-col tiles, 16 MFMAs/layer/wave).
// Per-SIMD MFMA work unchanged (2x16=32) but each wave's latency bubbles
// are filled by its SIMD-partner's MFMAs. R13's lesson (in-wave hybrid
// serializes) does not apply across waves.
//  - lane (n=lane&15,q=lane>>4): epilogue col = 32g+16*(q&1)+n; lanes q and
//    q+2 compute bit-identical hj (replicated C rows) and both write it
//    (same-addr same-value LDS write, benign); global out masked to q<2.
//  - staging: 512 thr, 1 half8 ds_write each; pchunk [32][8][16][2].
//  - keeps: L==2 static addressing, PRE=2*log2e prescale (absmax 0.0039
//    validated), shared zero C-in chains, xcq in tail, exp2/rcp tail.
// 64 WGs (1/CU) x 512 thr; launch_bounds(512,2) caps VGPR<=256.

typedef _Float16 half8 __attribute__((ext_vector_type(8)));
typedef float    f32x4 __attribute__((ext_vector_type(4)));

#define LGKM_BARRIER() asm volatile("s_waitcnt lgkmcnt(0)\n\ts_barrier" ::: "memory")

__device__ __forceinline__ half8 cvt8s(float4 v0, float4 v1, float s) {
    half8 hv;
    hv[0]=(_Float16)(v0.x*s); hv[1]=(_Float16)(v0.y*s);
    hv[2]=(_Float16)(v0.z*s); hv[3]=(_Float16)(v0.w*s);
    hv[4]=(_Float16)(v1.x*s); hv[5]=(_Float16)(v1.y*s);
    hv[6]=(_Float16)(v1.z*s); hv[7]=(_Float16)(v1.w*s);
    return hv;
}
__device__ __forceinline__ half8 cvt8(float4 v0, float4 v1) {
    half8 hv;
    hv[0]=(_Float16)v0.x; hv[1]=(_Float16)v0.y;
    hv[2]=(_Float16)v0.z; hv[3]=(_Float16)v0.w;
    hv[4]=(_Float16)v1.x; hv[5]=(_Float16)v1.y;
    hv[6]=(_Float16)v1.z; hv[7]=(_Float16)v1.w;
    return hv;
}

__global__ void __launch_bounds__(512, 2)
ltc_fused(const float* __restrict__ x,      // [B,T,128]
          const float* __restrict__ W_in,   // [256,128]
          const float* __restrict__ b_in,   // [256]
          const float* __restrict__ W_rec,  // [256,256]
          const float* __restrict__ b_rec,  // [256]
          const float* __restrict__ tau,    // [256]
          const int*   __restrict__ num_layers,
          float*       __restrict__ out,    // [B,256]
          int T)
{
    const int b    = blockIdx.x;
    const int tid  = threadIdx.x;
    const int lane = tid & 63;
    const int g    = tid >> 6;             // wave 0..7: out-cols [32g,32g+32)
    const int n    = lane & 15;
    const int q    = lane >> 4;
    const int t_my = q & 1;                // this lane's tile within the wave
    const int L    = num_layers[0];
    const int mycol = 32*g + 16*t_my + n;  // this lane's epilogue column
    const unsigned shamt = (unsigned)(t_my << 4);   // f16 select shift

    __shared__ _Float16 hbuf[2][256];           // h, PLAIN layout, dbuf
    __shared__ _Float16 xstage[2][16][16][8];   // x chunk, A-frag order
    __shared__ _Float16 pchunk[32][8][16][2];   // proj chunk [ts][g][n][t]

    // ---- stationary B-frags: W_rec (2x8) + W_in (2x4), f16, prescaled ----
    const float PRE = 2.8853900817779268f;      // 2*log2(e)
    half8 bh[2][8];
    half8 bx[2][4];
    float biasv[2];
#pragma unroll
    for (int t = 0; t < 2; ++t) {
        const int col = 32*g + 16*t + n;
        const float* rp = &W_rec[col * 256 + 8*q];
#pragma unroll
        for (int i = 0; i < 8; ++i)
            bh[t][i] = cvt8s(*(const float4*)&rp[32*i],
                             *(const float4*)&rp[32*i + 4], PRE);
        const float* ip = &W_in[col * 128 + 8*q];
#pragma unroll
        for (int i = 0; i < 4; ++i)
            bx[t][i] = cvt8s(*(const float4*)&ip[32*i],
                             *(const float4*)&ip[32*i + 4], PRE);
        biasv[t] = (b_in[col] + b_rec[col]) * PRE;
    }
    const float sj   = 0.1f / fminf(fmaxf(tau[mycol], 0.1f), 5.0f);
    const float nsj2 = -2.0f * sj;
    float hj = 0.0f;

    if (tid < 256) hbuf[0][tid] = (_Float16)0.0f;   // zero h buffer 0

    const float* xb  = x + (size_t)b * T * 128;
    const int    t_u = tid >> 4;           // staging: timestep in chunk 0..31
    const int    c16 = tid & 15;           // staging: 8-f32 kblock index
    const int    Mts = t_u >> 4, ms = t_u & 15;

    // ---- chunk-0 prefetch into registers (8 floats/thread) ----
    float4 xpreA, xpreB;
    {
        int tg = t_u; if (tg > T - 1) tg = T - 1;
        const float4* src = (const float4*)(xb + (size_t)tg * 128 + 8*c16);
        xpreA = src[0]; xpreB = src[1];
    }

// one recurrent layer: read hbuf[RB] (static), write hbuf[WB] (static)
#define LAYER(RB, WB, XCQ)                                                   \
    do {                                                                     \
        half8 ah[8];                                                         \
        _Pragma("unroll")                                                    \
        for (int i = 0; i < 8; ++i)                                          \
            ah[i] = *(const half8*)&hbuf[RB][32*i + 8*q];                    \
        const float term1 = __builtin_fmaf(sj, 1.0f - hj, hj);               \
        const f32x4 zz = (f32x4){0.f, 0.f, 0.f, 0.f};                        \
        f32x4 A0[2], A1[2], A2[2], A3[2];                                    \
        _Pragma("unroll")                                                    \
        for (int t = 0; t < 2; ++t) {                                        \
            A0[t] = __builtin_amdgcn_mfma_f32_16x16x32_f16(                  \
                ah[0], bh[t][0], zz, 0, 0, 0);                               \
            A1[t] = __builtin_amdgcn_mfma_f32_16x16x32_f16(                  \
                ah[2], bh[t][2], zz, 0, 0, 0);                               \
            A2[t] = __builtin_amdgcn_mfma_f32_16x16x32_f16(                  \
                ah[4], bh[t][4], zz, 0, 0, 0);                               \
            A3[t] = __builtin_amdgcn_mfma_f32_16x16x32_f16(                  \
                ah[6], bh[t][6], zz, 0, 0, 0);                               \
        }                                                                    \
        _Pragma("unroll")                                                    \
        for (int t = 0; t < 2; ++t) {                                        \
            A0[t] = __builtin_amdgcn_mfma_f32_16x16x32_f16(                  \
                ah[1], bh[t][1], A0[t], 0, 0, 0);                            \
            A1[t] = __builtin_amdgcn_mfma_f32_16x16x32_f16(                  \
                ah[3], bh[t][3], A1[t], 0, 0, 0);                            \
            A2[t] = __builtin_amdgcn_mfma_f32_16x16x32_f16(                  \
                ah[5], bh[t][5], A2[t], 0, 0, 0);                            \
            A3[t] = __builtin_amdgcn_mfma_f32_16x16x32_f16(                  \
                ah[7], bh[t][7], A3[t], 0, 0, 0);                            \
        }                                                                    \
        float s0 = t_my ? A0[1][0] : A0[0][0];                               \
        float s1 = t_my ? A1[1][0] : A1[0][0];                               \
        float s2 = t_my ? A2[1][0] : A2[0][0];                               \
        float s3 = t_my ? A3[1][0] : A3[0][0];                               \
        float z  = ((s0 + s1) + (s2 + s3)) + (XCQ);                          \
        float e  = __builtin_amdgcn_exp2f(z);     /* e^{2z}, prescaled */    \
        float rr = __builtin_amdgcn_rcpf(e + 1.0f);                          \
        hj = __builtin_fmaf(nsj2, rr, term1);     /* h + s*(tanh-h) */       \
        hbuf[WB][mycol] = (_Float16)hj;  /* q,q+2 write same value: benign */\
        LGKM_BARRIER();                                                      \
    } while (0)

#define STAGE_AND_PROJECT()                                                  \
    do {                                                                     \
        *(half8*)&xstage[Mts][c16][ms][0] = cvt8(xpreA, xpreB);              \
        __syncthreads();                                                     \
        _Pragma("unroll")                                                    \
        for (int Mt = 0; Mt < 2; ++Mt) {                                     \
            half8 ax[4];                                                     \
            _Pragma("unroll")                                                \
            for (int ks = 0; ks < 4; ++ks)                                   \
                ax[ks] = *(const half8*)&xstage[Mt][4*ks + q][n][0];         \
            f32x4 pa[2];                                                     \
            _Pragma("unroll")                                                \
            for (int t = 0; t < 2; ++t)                                      \
                pa[t] = (f32x4){biasv[t], biasv[t], biasv[t], biasv[t]};     \
            _Pragma("unroll")                                                \
            for (int ks = 0; ks < 4; ++ks)                                   \
                _Pragma("unroll")                                            \
                for (int t = 0; t < 2; ++t)                                  \
                    pa[t] = __builtin_amdgcn_mfma_f32_16x16x32_f16(          \
                        ax[ks], bx[t][ks], pa[t], 0, 0, 0);                  \
            _Pragma("unroll")                                                \
            for (int r = 0; r < 4; ++r) {                                    \
                union { _Float16 h[2]; unsigned u; } pk;                     \
                pk.h[0] = (_Float16)pa[0][r];                                \
                pk.h[1] = (_Float16)pa[1][r];                                \
                *(unsigned*)&pchunk[16*Mt + 4*q + r][g][n][0] = pk.u;        \
            }                                                                \
        }                                                                    \
        __syncthreads();                                                     \
    } while (0)

#define PREFETCH_NEXT()                                                      \
    do {                                                                     \
        const int nc = (tc + 32 < T) ? tc + 32 : tc;                         \
        int tg = nc + t_u; if (tg > T - 1) tg = T - 1;                       \
        const float4* src = (const float4*)(xb + (size_t)tg * 128 + 8*c16);  \
        xpreA = src[0]; xpreB = src[1];                                      \
    } while (0)

#define XCQ_LOAD(TS)                                                         \
    float xcq;                                                               \
    {                                                                        \
        unsigned d = *(const unsigned*)&pchunk[TS][g][n][0];                 \
        d >>= shamt;                                                         \
        union { unsigned u; _Float16 h[2]; } uu; uu.u = d;                   \
        xcq = (float)uu.h[0];                                                \
    }

    if (L == 2) {
        // ======== specialized L==2 path: fully static LDS addressing ====
        for (int tc = 0; tc < T; tc += 32) {
            STAGE_AND_PROJECT();
            PREFETCH_NEXT();
            const int tlen = (T - tc < 32) ? (T - tc) : 32;
#pragma unroll 2
            for (int ts = 0; ts < tlen; ++ts) {
                XCQ_LOAD(ts);
                LAYER(0, 1, xcq);   // layer 1: buf0 -> buf1
                LAYER(1, 0, xcq);   // layer 2: buf1 -> buf0
            }
        }
    } else {
        // ======== generic-L fallback ====================================
        int hb = 0;
        for (int tc = 0; tc < T; tc += 32) {
            STAGE_AND_PROJECT();
            PREFETCH_NEXT();
            const int tlen = (T - tc < 32) ? (T - tc) : 32;
            for (int ts = 0; ts < tlen; ++ts) {
                XCQ_LOAD(ts);
                for (int l = 0; l < L; ++l) {
                    if (hb == 0) LAYER(0, 1, xcq);
                    else         LAYER(1, 0, xcq);
                    hb ^= 1;
                }
            }
        }
    }
#undef LAYER
#undef STAGE_AND_PROJECT
#undef PREFETCH_NEXT
#undef XCQ_LOAD

    if (q < 2)
        out[(size_t)b * 256 + mycol] = hj;
}

extern "C" void kernel_launch(void* const* d_in, const int* in_sizes, int n_in,
                              void* d_out, int out_size, void* d_ws, size_t ws_size,
                              hipStream_t stream) {
    const float* x     = (const float*)d_in[0];
    const float* W_in  = (const float*)d_in[1];
    const float* b_in  = (const float*)d_in[2];
    const float* W_rec = (const float*)d_in[3];
    const float* b_rec = (const float*)d_in[4];
    const float* tau   = (const float*)d_in[5];
    const int*   numl  = (const int*)d_in[6];

    const int H = in_sizes[2];            // 256
    const int I = in_sizes[1] / H;        // 128
    const int B = out_size / H;           // 64
    const int T = in_sizes[0] / (B * I);  // 4096

    ltc_fused<<<B, 512, 0, stream>>>(x, W_in, b_in, W_rec, b_rec, tau,
                                     numl, (float*)d_out, T);
}